// Round 1
// baseline (920.479 us; speedup 1.0000x reference)
//
#include <hip/hip_runtime.h>
#include <stdint.h>

#define N_PTS   8192
#define D       256
#define N_E     8192
#define BETA    0.25f
#define EPS_1   1.0000001f   // 1 + 1e-7 (rounds to 1+ulp in f32, same as jnp)

typedef unsigned long long u64;

// ---------------- init workspace ----------------
__global__ void k_init(u64* keys, float* counts, double* loss_sum) {
    int i = blockIdx.x * blockDim.x + threadIdx.x;
    if (i < N_E)  counts[i] = 0.f;
    if (i < N_PTS) keys[i] = ~0ULL;
    if (i == 0)   *loss_sum = 0.0;
}

// ---------------- argmin over codes (fused matmul + argmin) ----------------
#define BM 32
#define BN 128
#define BK 32
#define CS 4                                 // code splits
#define CODES_PER_BLK (N_E / CS)             // 2048
#define JT (CODES_PER_BLK / BN)              // 16
#define KC (D / BK)                          // 8

__global__ __launch_bounds__(256, 2) void k_argmin(
    const float* __restrict__ u, const float* __restrict__ cb,
    u64* __restrict__ keys)
{
    __shared__ float Asm[D][BM + 4];         // A^T, sign-folded: [256][36] = 36 KB
    __shared__ float Bsm[BK][BN + 4];        // B^T chunk:        [32][132] = 16.5 KB

    const int t  = threadIdx.x;
    const int bx = blockIdx.x;
    const int rb = bx >> 2;                  // row block
    const int cs = bx & (CS - 1);            // code split
    const int r0 = rb * BM;
    const int cbase = cs * CODES_PER_BLK;
    const int tx = t & 31, ty = t >> 5;      // 32 x 8 thread grid; micro-tile 4x4

    // stage A once: 32 rows x 256 K, transposed into LDS, Minkowski sign folded
    for (int p = 0; p < BM; ++p) {
        float v = u[(r0 + p) * D + t];       // t indexes k (0..255): coalesced
        if (t == 0) v = -v;                  // signs = (-,+,+,...)
        Asm[t][p] = v;
    }
    __syncthreads();

    u64 best[4] = {~0ULL, ~0ULL, ~0ULL, ~0ULL};
    float acc[4][4];

    for (int jt = 0; jt < JT; ++jt) {
        const int c0 = cbase + jt * BN;
        #pragma unroll
        for (int i = 0; i < 4; ++i)
            #pragma unroll
            for (int j = 0; j < 4; ++j) acc[i][j] = 0.f;

        for (int kc = 0; kc < KC; ++kc) {
            __syncthreads();                 // protect Bsm from prev compute
            // stage B: codes c0..c0+127, k = kc*32..+31 (transposed)
            #pragma unroll
            for (int p = 0; p < 16; ++p) {
                int k = t & 31;
                int c = (t >> 5) + p * 8;
                Bsm[k][c] = cb[(c0 + c) * D + kc * BK + k];
            }
            __syncthreads();
            #pragma unroll
            for (int k = 0; k < BK; ++k) {
                const float4 a4 = *(const float4*)&Asm[kc * BK + k][ty * 4];
                const float4 b4 = *(const float4*)&Bsm[k][tx * 4];
                acc[0][0] += a4.x * b4.x; acc[0][1] += a4.x * b4.y;
                acc[0][2] += a4.x * b4.z; acc[0][3] += a4.x * b4.w;
                acc[1][0] += a4.y * b4.x; acc[1][1] += a4.y * b4.y;
                acc[1][2] += a4.y * b4.z; acc[1][3] += a4.y * b4.w;
                acc[2][0] += a4.z * b4.x; acc[2][1] += a4.z * b4.y;
                acc[2][2] += a4.z * b4.z; acc[2][3] += a4.z * b4.w;
                acc[3][0] += a4.w * b4.x; acc[3][1] += a4.w * b4.y;
                acc[3][2] += a4.w * b4.z; acc[3][3] += a4.w * b4.w;
            }
        }

        // fold this 128-code tile into per-row running best
        #pragma unroll
        for (int i = 0; i < 4; ++i) {
            u64 kmin = ~0ULL;
            #pragma unroll
            for (int j = 0; j < 4; ++j) {
                // acc = K = <u~, c>;  m = max(-K, 1+eps) >= 1 > 0
                float m = fmaxf(-acc[i][j], EPS_1);
                u64 key = ((u64)__float_as_uint(m) << 32)
                        | (unsigned)(c0 + tx * 4 + j);
                kmin = key < kmin ? key : kmin;
            }
            // reduce across the 32 tx-lanes sharing this row (within half-wave)
            #pragma unroll
            for (int s = 16; s >= 1; s >>= 1) {
                u64 o = __shfl_xor(kmin, s);
                kmin = o < kmin ? o : kmin;
            }
            best[i] = kmin < best[i] ? kmin : best[i];
        }
    }

    if (tx == 0) {
        #pragma unroll
        for (int i = 0; i < 4; ++i)
            atomicMin(&keys[r0 + ty * 4 + i], best[i]);
    }
}

// ---------------- gather z_q, per-pair distance, histogram ----------------
__global__ __launch_bounds__(256) void k_gather(
    const float* __restrict__ u, const float* __restrict__ cb,
    const u64* __restrict__ keys, float* __restrict__ out,
    float* __restrict__ counts, double* __restrict__ loss_sum)
{
    const int t    = threadIdx.x;
    const int row  = blockIdx.x * 4 + (t >> 6);   // 4 waves/block, 1 row/wave
    const int lane = t & 63;
    const u64 key  = keys[row];
    const int idx  = (int)(unsigned)(key & 0xffffffffULL);

    float* zq = out + 1;                          // z_q region of d_out
    float partial = 0.f;
    #pragma unroll
    for (int q = 0; q < 4; ++q) {
        int e = q * 64 + lane;                    // coalesced
        float uv = u[(size_t)row * D + e];
        float cv = cb[(size_t)idx * D + e];
        partial += (e == 0) ? -uv * cv : uv * cv; // Lorentzian inner
        zq[(size_t)row * D + e] = cv;             // z_q forward == x_q
    }
    #pragma unroll
    for (int s = 32; s >= 1; s >>= 1)
        partial += __shfl_xor(partial, s);

    if (lane == 0) {
        float m = fmaxf(-partial, EPS_1);
        float dist = acoshf(m);
        atomicAdd(loss_sum, (double)dist);
        atomicAdd(&counts[idx], 1.f);
    }
}

// ---------------- entropy / perplexity / e_mean / loss scalars ----------------
__global__ __launch_bounds__(256) void k_final(
    const float* __restrict__ counts, const double* __restrict__ loss_sum,
    float* __restrict__ out)
{
    __shared__ float red[256];
    const int t = threadIdx.x;
    const int OFF_P = 1 + N_PTS * D;             // perplexity slot
    float ent = 0.f;
    for (int i = t; i < N_E; i += 256) {
        float e = counts[i] * (1.0f / N_PTS);
        out[OFF_P + 2 + i] = e;                  // e_mean
        ent -= e * logf(e + 1e-10f);
    }
    red[t] = ent;
    __syncthreads();
    for (int s = 128; s > 0; s >>= 1) {
        if (t < s) red[t] += red[t + s];
        __syncthreads();
    }
    if (t == 0) {
        float entropy = red[0];
        out[0]         = (1.0f + BETA) * (float)(*loss_sum / (double)N_PTS); // loss
        out[OFF_P]     = expf(entropy);          // perplexity
        out[OFF_P + 1] = entropy;                // diversity_loss
    }
}

// ---------------- launch ----------------
extern "C" void kernel_launch(void* const* d_in, const int* in_sizes, int n_in,
                              void* d_out, int out_size, void* d_ws, size_t ws_size,
                              hipStream_t stream)
{
    const float* u  = (const float*)d_in[0];
    const float* cb = (const float*)d_in[1];
    float* out = (float*)d_out;

    u64*    keys     = (u64*)d_ws;
    float*  counts   = (float*)((char*)d_ws + N_PTS * sizeof(u64));
    double* loss_sum = (double*)((char*)d_ws + N_PTS * sizeof(u64) + N_E * sizeof(float));

    k_init  <<<(N_E + 255) / 256, 256, 0, stream>>>(keys, counts, loss_sum);
    k_argmin<<<(N_PTS / BM) * CS, 256, 0, stream>>>(u, cb, keys);
    k_gather<<<N_PTS / 4, 256, 0, stream>>>(u, cb, keys, out, counts, loss_sum);
    k_final <<<1, 256, 0, stream>>>(counts, loss_sum, out);
}

// Round 2
// 270.085 us; speedup vs baseline: 3.4081x; 3.4081x over previous
//
#include <hip/hip_runtime.h>
#include <hip/hip_bf16.h>
#include <stdint.h>

#define N_PTS   8192
#define D       256
#define N_E     8192
#define BETA    0.25f
#define EPS_1   1.0000001f   // 1 + 1e-7 (rounds to 1+ulp in f32, same as jnp)

typedef unsigned long long u64;
typedef __attribute__((ext_vector_type(8))) short bf16x8;   // 8 bf16 = 4 VGPR
typedef __attribute__((ext_vector_type(4))) float f32x4;

// ---- workspace layout (bytes) ----
#define WS_KEYS   0
#define WS_COUNTS (N_PTS * 8)                    // 64 KB
#define WS_LOSS   (WS_COUNTS + N_E * 4)          // +32 KB
#define WS_AHI    (1 << 20)                      // 1 MB, aligned
#define WS_ALO    (WS_AHI + N_PTS * D * 2)
#define WS_BHI    (WS_ALO + N_PTS * D * 2)
#define WS_BLO    (WS_BHI + N_E * D * 2)         // total ~17 MB

__device__ __forceinline__ short f2bf(float x) {
    __hip_bfloat16 h = __float2bfloat16(x);      // RTN-even
    return *reinterpret_cast<short*>(&h);
}
__device__ __forceinline__ float bf2f(short s) {
    __hip_bfloat16 h = *reinterpret_cast<__hip_bfloat16*>(&s);
    return __bfloat162float(h);
}

#define GLOAD16(gp, lp) __builtin_amdgcn_global_load_lds(                      \
    (const __attribute__((address_space(1))) void*)(gp),                       \
    (__attribute__((address_space(3))) void*)(lp), 16, 0, 0)

// ---------------- init workspace ----------------
__global__ void k_init(u64* keys, float* counts, double* loss_sum) {
    int i = blockIdx.x * blockDim.x + threadIdx.x;
    if (i < N_E)   counts[i] = 0.f;
    if (i < N_PTS) keys[i] = ~0ULL;
    if (i == 0)    *loss_sum = 0.0;
}

// ---------------- split f32 -> bf16 hi/lo (sign-folded for u) ----------------
__global__ __launch_bounds__(256) void k_prep(
    const float* __restrict__ u, const float* __restrict__ cb,
    short* __restrict__ Ahi, short* __restrict__ Alo,
    short* __restrict__ Bhi, short* __restrict__ Blo)
{
    int e = (blockIdx.x * 256 + threadIdx.x) * 4;
    if (e >= N_PTS * D) return;

    float4 v = *(const float4*)&u[e];
    if ((e & (D - 1)) == 0) v.x = -v.x;          // Minkowski sign fold, k=0
    short4 hi, lo;
    {
        float x;
        x = v.x; hi.x = f2bf(x); lo.x = f2bf(x - bf2f(hi.x));
        x = v.y; hi.y = f2bf(x); lo.y = f2bf(x - bf2f(hi.y));
        x = v.z; hi.z = f2bf(x); lo.z = f2bf(x - bf2f(hi.z));
        x = v.w; hi.w = f2bf(x); lo.w = f2bf(x - bf2f(hi.w));
    }
    *(short4*)&Ahi[e] = hi;
    *(short4*)&Alo[e] = lo;

    float4 w = *(const float4*)&cb[e];
    {
        float x;
        x = w.x; hi.x = f2bf(x); lo.x = f2bf(x - bf2f(hi.x));
        x = w.y; hi.y = f2bf(x); lo.y = f2bf(x - bf2f(hi.y));
        x = w.z; hi.z = f2bf(x); lo.z = f2bf(x - bf2f(hi.z));
        x = w.w; hi.w = f2bf(x); lo.w = f2bf(x - bf2f(hi.w));
    }
    *(short4*)&Bhi[e] = hi;
    *(short4*)&Blo[e] = lo;
}

// ---------------- MFMA argmin: C = A~ . B^T, per-row argmin, no C write ------
// split-bf16: a.b = ahi.bhi + ahi.blo + alo.bhi  (err ~2^-18 rel, safe margin)
#define BMM 128
#define BNN 128
#define BKK 32
#define NKS (D / BKK)        // 8

__global__ __launch_bounds__(256, 2) void k_argmin_mfma(
    const short* __restrict__ Ahi, const short* __restrict__ Alo,
    const short* __restrict__ Bhi, const short* __restrict__ Blo,
    u64* __restrict__ keys)
{
    __shared__ short sA[2][BMM * BKK];   // [hi/lo][128*32] = 2 x 8 KB
    __shared__ short sB[2][BNN * BKK];   // 2 x 8 KB   (32 KB total)

    const int t  = threadIdx.x;
    const int w  = t >> 6;               // wave 0..3
    const int l  = t & 63;
    const int rb = blockIdx.x >> 6;      // 64 row-blocks (points)
    const int cbk = blockIdx.x & 63;     // 64 col-blocks (codes)
    const int r0 = rb * BMM;
    const int c0 = cbk * BNN;
    const int wr = w >> 1, wc = w & 1;   // 2x2 wave grid, 64x64 each

    f32x4 acc[4][4];
    #pragma unroll
    for (int i = 0; i < 4; ++i)
        #pragma unroll
        for (int j = 0; j < 4; ++j) acc[i][j] = (f32x4){0.f, 0.f, 0.f, 0.f};

    const int lrow = l >> 2;             // 0..15: row within 16-row stage slice
    const int lcol = (l & 3) * 8;        // 0/8/16/24: k-element offset

    for (int kk = 0; kk < NKS; ++kk) {
        __syncthreads();                 // prev compute done before overwrite
        const int k0 = kk * BKK;
        #pragma unroll
        for (int i = 0; i < 2; ++i) {
            const int srow = w * 32 + i * 16;            // wave-uniform
            const size_t ga = (size_t)(r0 + srow + lrow) * D + k0 + lcol;
            const size_t gb = (size_t)(c0 + srow + lrow) * D + k0 + lcol;
            GLOAD16(Ahi + ga, &sA[0][srow * BKK]);
            GLOAD16(Alo + ga, &sA[1][srow * BKK]);
            GLOAD16(Bhi + gb, &sB[0][srow * BKK]);
            GLOAD16(Blo + gb, &sB[1][srow * BKK]);
        }
        __syncthreads();                 // drains vmcnt: tiles ready

        bf16x8 ah[4], al[4], bh[4], bl[4];
        const int ko = (l >> 4) * 8;     // k-offset within frag
        #pragma unroll
        for (int f = 0; f < 4; ++f) {
            const int ra = (wr * 64 + f * 16 + (l & 15)) * BKK + ko;
            ah[f] = *(const bf16x8*)&sA[0][ra];
            al[f] = *(const bf16x8*)&sA[1][ra];
            const int rbx = (wc * 64 + f * 16 + (l & 15)) * BKK + ko;
            bh[f] = *(const bf16x8*)&sB[0][rbx];
            bl[f] = *(const bf16x8*)&sB[1][rbx];
        }
        #pragma unroll
        for (int mf = 0; mf < 4; ++mf)
            #pragma unroll
            for (int nf = 0; nf < 4; ++nf) {
                acc[mf][nf] = __builtin_amdgcn_mfma_f32_16x16x32_bf16(
                    ah[mf], bh[nf], acc[mf][nf], 0, 0, 0);
                acc[mf][nf] = __builtin_amdgcn_mfma_f32_16x16x32_bf16(
                    ah[mf], bl[nf], acc[mf][nf], 0, 0, 0);
                acc[mf][nf] = __builtin_amdgcn_mfma_f32_16x16x32_bf16(
                    al[mf], bh[nf], acc[mf][nf], 0, 0, 0);
            }
    }

    // epilogue: per-row argmin over this block's 128 codes, then atomicMin
    // C/D layout (m89-verified): col = lane&15, row = (lane>>4)*4 + reg
    const int g  = l >> 4;
    const int cc = l & 15;
    #pragma unroll
    for (int mf = 0; mf < 4; ++mf) {
        #pragma unroll
        for (int r = 0; r < 4; ++r) {
            u64 km = ~0ULL;
            #pragma unroll
            for (int nf = 0; nf < 4; ++nf) {
                float m = fmaxf(-acc[mf][nf][r], EPS_1);   // m >= 1 > 0
                unsigned code = (unsigned)(c0 + wc * 64 + nf * 16 + cc);
                u64 key = ((u64)__float_as_uint(m) << 32) | code;
                km = key < km ? key : km;
            }
            #pragma unroll
            for (int s = 8; s >= 1; s >>= 1) {             // 16-lane col groups
                u64 o = __shfl_xor(km, s);
                km = o < km ? o : km;
            }
            if (cc == 0)
                atomicMin(&keys[r0 + wr * 64 + mf * 16 + g * 4 + r], km);
        }
    }
}

// ---------------- gather z_q, per-pair f32 distance, histogram ----------------
__global__ __launch_bounds__(256) void k_gather(
    const float* __restrict__ u, const float* __restrict__ cb,
    const u64* __restrict__ keys, float* __restrict__ out,
    float* __restrict__ counts, double* __restrict__ loss_sum)
{
    const int t    = threadIdx.x;
    const int row  = blockIdx.x * 4 + (t >> 6);
    const int lane = t & 63;
    const u64 key  = keys[row];
    const int idx  = (int)(unsigned)(key & 0xffffffffULL);

    float* zq = out + 1;
    float partial = 0.f;
    #pragma unroll
    for (int q = 0; q < 4; ++q) {
        int e = q * 64 + lane;
        float uv = u[(size_t)row * D + e];
        float cv = cb[(size_t)idx * D + e];
        partial += (e == 0) ? -uv * cv : uv * cv;
        zq[(size_t)row * D + e] = cv;
    }
    #pragma unroll
    for (int s = 32; s >= 1; s >>= 1)
        partial += __shfl_xor(partial, s);

    if (lane == 0) {
        float m = fmaxf(-partial, EPS_1);
        float dist = acoshf(m);
        atomicAdd(loss_sum, (double)dist);
        atomicAdd(&counts[idx], 1.f);
    }
}

// ---------------- scalars: loss, perplexity, entropy, e_mean -----------------
__global__ __launch_bounds__(256) void k_final(
    const float* __restrict__ counts, const double* __restrict__ loss_sum,
    float* __restrict__ out)
{
    __shared__ float red[256];
    const int t = threadIdx.x;
    const int OFF_P = 1 + N_PTS * D;
    float ent = 0.f;
    for (int i = t; i < N_E; i += 256) {
        float e = counts[i] * (1.0f / N_PTS);
        out[OFF_P + 2 + i] = e;
        ent -= e * logf(e + 1e-10f);
    }
    red[t] = ent;
    __syncthreads();
    for (int s = 128; s > 0; s >>= 1) {
        if (t < s) red[t] += red[t + s];
        __syncthreads();
    }
    if (t == 0) {
        float entropy = red[0];
        out[0]         = (1.0f + BETA) * (float)(*loss_sum / (double)N_PTS);
        out[OFF_P]     = expf(entropy);
        out[OFF_P + 1] = entropy;
    }
}

// ---------------- launch ----------------
extern "C" void kernel_launch(void* const* d_in, const int* in_sizes, int n_in,
                              void* d_out, int out_size, void* d_ws, size_t ws_size,
                              hipStream_t stream)
{
    const float* u  = (const float*)d_in[0];
    const float* cb = (const float*)d_in[1];
    float* out = (float*)d_out;
    char* ws = (char*)d_ws;

    u64*    keys     = (u64*)(ws + WS_KEYS);
    float*  counts   = (float*)(ws + WS_COUNTS);
    double* loss_sum = (double*)(ws + WS_LOSS);
    short*  Ahi = (short*)(ws + WS_AHI);
    short*  Alo = (short*)(ws + WS_ALO);
    short*  Bhi = (short*)(ws + WS_BHI);
    short*  Blo = (short*)(ws + WS_BLO);

    k_init<<<(N_E + 255) / 256, 256, 0, stream>>>(keys, counts, loss_sum);
    k_prep<<<(N_PTS * D / 4 + 255) / 256, 256, 0, stream>>>(u, cb, Ahi, Alo, Bhi, Blo);
    k_argmin_mfma<<<(N_PTS / BMM) * (N_E / BNN), 256, 0, stream>>>(Ahi, Alo, Bhi, Blo, keys);
    k_gather<<<N_PTS / 4, 256, 0, stream>>>(u, cb, keys, out, counts, loss_sum);
    k_final<<<1, 256, 0, stream>>>(counts, loss_sum, out);
}

// Round 3
// 226.499 us; speedup vs baseline: 4.0639x; 1.1924x over previous
//
#include <hip/hip_runtime.h>
#include <hip/hip_bf16.h>
#include <stdint.h>

#define N_PTS   8192
#define D       256
#define N_E     8192
#define BETA    0.25f
#define EPS_1   1.0000001f   // 1 + 1e-7 (rounds to 1+ulp in f32, same as jnp)

typedef unsigned long long u64;
typedef __attribute__((ext_vector_type(8))) short bf16x8;   // 8 bf16 = 4 VGPR
typedef __attribute__((ext_vector_type(8))) short short8;
typedef __attribute__((ext_vector_type(4))) float f32x4;

// ---- workspace layout (bytes) ----
// Fragment-linear bf16 arrays: element (p,k) of an 8192x256 matrix lives at
//   blk = (p>>4)*8 + (k>>5);  l = ((k>>3)&3)*16 + (p&15);  j = k&7
//   idx = blk*512 + l*8 + j
// so each 16x32 MFMA fragment is a contiguous 1KB block in lane-major order:
// global_load_lds(uniform base + lane*16) and ds_read_b128(lane*16) are both
// perfectly linear -> zero bank conflicts.
#define WS_KEYS   0
#define WS_COUNTS (N_PTS * 8)                    // 64 KB
#define WS_LOSS   (WS_COUNTS + N_E * 4)          // +32 KB
#define WS_AHI    (1 << 20)                      // 1 MB-aligned
#define WS_ALO    (WS_AHI + N_PTS * D * 2)
#define WS_BHI    (WS_ALO + N_PTS * D * 2)
#define WS_BLO    (WS_BHI + N_E * D * 2)         // total ~17 MB

__device__ __forceinline__ short f2bf(float x) {
    __hip_bfloat16 h = __float2bfloat16(x);      // RTN-even
    return *reinterpret_cast<short*>(&h);
}
__device__ __forceinline__ float bf2f(short s) {
    __hip_bfloat16 h = *reinterpret_cast<__hip_bfloat16*>(&s);
    return __bfloat162float(h);
}

#define GLOAD16(gp, lp) __builtin_amdgcn_global_load_lds(                      \
    (const __attribute__((address_space(1))) void*)(gp),                       \
    (__attribute__((address_space(3))) void*)(lp), 16, 0, 0)

// ------- init + split f32 -> bf16 hi/lo, fragment-linear layout -------------
__global__ __launch_bounds__(256) void k_prep(
    const float* __restrict__ u, const float* __restrict__ cb,
    short* __restrict__ Ahi, short* __restrict__ Alo,
    short* __restrict__ Bhi, short* __restrict__ Blo,
    u64* __restrict__ keys, float* __restrict__ counts,
    double* __restrict__ loss_sum)
{
    const int tid = blockIdx.x * 256 + threadIdx.x;   // 0 .. 262143
    if (tid < N_E)   counts[tid] = 0.f;
    if (tid < N_PTS) keys[tid] = ~0ULL;
    if (tid == 0)    *loss_sum = 0.0;

    const int blk = tid >> 6;            // = (p>>4)*8 + (k>>5)
    const int l   = tid & 63;
    const int s   = blk >> 3, c = blk & 7;
    const int p   = s * 16 + (l & 15);
    const int k   = c * 32 + (l >> 4) * 8;
    const size_t gin  = (size_t)p * D + k;
    const size_t gout = (size_t)tid * 8;

    float v[8];
    short8 h8, l8;

    *(float4*)&v[0] = *(const float4*)&u[gin];
    *(float4*)&v[4] = *(const float4*)&u[gin + 4];
    if (k == 0) v[0] = -v[0];            // Minkowski sign fold on time comp
    #pragma unroll
    for (int j = 0; j < 8; ++j) {
        h8[j] = f2bf(v[j]);
        l8[j] = f2bf(v[j] - bf2f(h8[j]));
    }
    *(short8*)&Ahi[gout] = h8;
    *(short8*)&Alo[gout] = l8;

    *(float4*)&v[0] = *(const float4*)&cb[gin];
    *(float4*)&v[4] = *(const float4*)&cb[gin + 4];
    #pragma unroll
    for (int j = 0; j < 8; ++j) {
        h8[j] = f2bf(v[j]);
        l8[j] = f2bf(v[j] - bf2f(h8[j]));
    }
    *(short8*)&Bhi[gout] = h8;
    *(short8*)&Blo[gout] = l8;
}

// ---------------- MFMA argmin: C = A~ . B^T, per-row argmin, no C write ------
// split-bf16: a.b = ahi.bhi + ahi.blo + alo.bhi  (err ~2^-18 rel, safe margin)
#define BMM 128
#define BNN 128
#define BKK 32
#define NKS (D / BKK)        // 8

__global__ __launch_bounds__(256, 4) void k_argmin_mfma(
    const short* __restrict__ Ahi, const short* __restrict__ Alo,
    const short* __restrict__ Bhi, const short* __restrict__ Blo,
    u64* __restrict__ keys)
{
    __shared__ short sm[4][8 * 512];     // Ahi,Alo,Bhi,Blo: 8 KB each = 32 KB

    const int t   = threadIdx.x;
    const int w   = t >> 6;              // wave 0..3
    const int l   = t & 63;
    const int bid = blockIdx.x;          // 4096 = 64 rb x 64 cb
    const int xcd = bid & 7;             // XCD-chunked swizzle (nwg%8==0)
    const int ii  = bid >> 3;
    const int rb  = xcd * 8 + (ii >> 6);
    const int cbk = ii & 63;
    const int r0  = rb * BMM, c0 = cbk * BNN;
    const int wr  = w >> 1, wc = w & 1;  // 2x2 wave grid, 64x64 each

    // staging: wave w owns one array; 8 fragment-blocks of 1KB per K-step
    const short* gsrc = (w == 0) ? Ahi : (w == 1) ? Alo : (w == 2) ? Bhi : Blo;
    short* ldst = sm[w];
    const int s0 = ((w < 2) ? rb : cbk) * 8;   // first 16-row slice index

    f32x4 acc[4][4];
    #pragma unroll
    for (int i = 0; i < 4; ++i)
        #pragma unroll
        for (int j = 0; j < 4; ++j) acc[i][j] = (f32x4){0.f, 0.f, 0.f, 0.f};

    for (int kk = 0; kk < NKS; ++kk) {
        __syncthreads();                 // prev compute done before overwrite
        #pragma unroll
        for (int i = 0; i < 8; ++i)
            GLOAD16(gsrc + (size_t)((s0 + i) * 8 + kk) * 512 + l * 8,
                    ldst + i * 512);
        __syncthreads();                 // drains vmcnt: tiles ready

        bf16x8 ah[4], al[4], bh[4], bl[4];
        #pragma unroll
        for (int f = 0; f < 4; ++f) {
            ah[f] = *(const bf16x8*)&sm[0][(wr * 4 + f) * 512 + l * 8];
            al[f] = *(const bf16x8*)&sm[1][(wr * 4 + f) * 512 + l * 8];
            bh[f] = *(const bf16x8*)&sm[2][(wc * 4 + f) * 512 + l * 8];
            bl[f] = *(const bf16x8*)&sm[3][(wc * 4 + f) * 512 + l * 8];
        }
        #pragma unroll
        for (int mf = 0; mf < 4; ++mf)
            #pragma unroll
            for (int nf = 0; nf < 4; ++nf) {
                acc[mf][nf] = __builtin_amdgcn_mfma_f32_16x16x32_bf16(
                    ah[mf], bh[nf], acc[mf][nf], 0, 0, 0);
                acc[mf][nf] = __builtin_amdgcn_mfma_f32_16x16x32_bf16(
                    ah[mf], bl[nf], acc[mf][nf], 0, 0, 0);
                acc[mf][nf] = __builtin_amdgcn_mfma_f32_16x16x32_bf16(
                    al[mf], bh[nf], acc[mf][nf], 0, 0, 0);
            }
    }

    // epilogue: per-row argmin over this block's 128 codes, then atomicMin
    // C/D layout (m89-verified): col = lane&15, row = (lane>>4)*4 + reg
    const int g  = l >> 4;
    const int cc = l & 15;
    #pragma unroll
    for (int mf = 0; mf < 4; ++mf) {
        #pragma unroll
        for (int r = 0; r < 4; ++r) {
            u64 km = ~0ULL;
            #pragma unroll
            for (int nf = 0; nf < 4; ++nf) {
                float m = fmaxf(-acc[mf][nf][r], EPS_1);   // m >= 1 > 0
                unsigned code = (unsigned)(c0 + wc * 64 + nf * 16 + cc);
                u64 key = ((u64)__float_as_uint(m) << 32) | code;
                km = key < km ? key : km;
            }
            #pragma unroll
            for (int s = 8; s >= 1; s >>= 1) {             // 16-lane col groups
                u64 o = __shfl_xor(km, s);
                km = o < km ? o : km;
            }
            if (cc == 0)
                atomicMin(&keys[r0 + wr * 64 + mf * 16 + g * 4 + r], km);
        }
    }
}

// ---------------- gather z_q, per-pair f32 distance, histogram ----------------
__global__ __launch_bounds__(256) void k_gather(
    const float* __restrict__ u, const float* __restrict__ cb,
    const u64* __restrict__ keys, float* __restrict__ out,
    float* __restrict__ counts, double* __restrict__ loss_sum)
{
    __shared__ float sred[4];
    const int t    = threadIdx.x;
    const int w    = t >> 6;
    const int row  = blockIdx.x * 4 + w;
    const int lane = t & 63;
    const u64 key  = keys[row];
    const int idx  = (int)(unsigned)(key & 0xffffffffULL);

    float* zq = out + 1;
    float4 uv = *(const float4*)&u[(size_t)row * D + lane * 4];
    float4 cv = *(const float4*)&cb[(size_t)idx * D + lane * 4];
    if (lane == 0) uv.x = -uv.x;                  // Lorentzian sign
    float partial = uv.x * cv.x + uv.y * cv.y + uv.z * cv.z + uv.w * cv.w;
    *(float4*)&zq[(size_t)row * D + lane * 4] = cv;

    #pragma unroll
    for (int s = 32; s >= 1; s >>= 1)
        partial += __shfl_xor(partial, s);

    if (lane == 0) {
        float m = fmaxf(-partial, EPS_1);
        sred[w] = acoshf(m);
        atomicAdd(&counts[idx], 1.f);             // scattered: low contention
    }
    __syncthreads();
    if (t == 0)                                   // 1 f64 atomic per block
        atomicAdd(loss_sum, (double)(sred[0] + sred[1] + sred[2] + sred[3]));
}

// ---------------- scalars: loss, perplexity, entropy, e_mean -----------------
__global__ __launch_bounds__(256) void k_final(
    const float* __restrict__ counts, const double* __restrict__ loss_sum,
    float* __restrict__ out)
{
    __shared__ float red[256];
    const int t = threadIdx.x;
    const int OFF_P = 1 + N_PTS * D;
    float ent = 0.f;
    for (int i = t; i < N_E; i += 256) {
        float e = counts[i] * (1.0f / N_PTS);
        out[OFF_P + 2 + i] = e;
        ent -= e * logf(e + 1e-10f);
    }
    red[t] = ent;
    __syncthreads();
    for (int s = 128; s > 0; s >>= 1) {
        if (t < s) red[t] += red[t + s];
        __syncthreads();
    }
    if (t == 0) {
        float entropy = red[0];
        out[0]         = (1.0f + BETA) * (float)(*loss_sum / (double)N_PTS);
        out[OFF_P]     = expf(entropy);
        out[OFF_P + 1] = entropy;
    }
}

// ---------------- launch ----------------
extern "C" void kernel_launch(void* const* d_in, const int* in_sizes, int n_in,
                              void* d_out, int out_size, void* d_ws, size_t ws_size,
                              hipStream_t stream)
{
    const float* u  = (const float*)d_in[0];
    const float* cb = (const float*)d_in[1];
    float* out = (float*)d_out;
    char* ws = (char*)d_ws;

    u64*    keys     = (u64*)(ws + WS_KEYS);
    float*  counts   = (float*)(ws + WS_COUNTS);
    double* loss_sum = (double*)(ws + WS_LOSS);
    short*  Ahi = (short*)(ws + WS_AHI);
    short*  Alo = (short*)(ws + WS_ALO);
    short*  Bhi = (short*)(ws + WS_BHI);
    short*  Blo = (short*)(ws + WS_BLO);

    k_prep<<<N_PTS * D / 8 / 256, 256, 0, stream>>>(u, cb, Ahi, Alo, Bhi, Blo,
                                                    keys, counts, loss_sum);
    k_argmin_mfma<<<(N_PTS / BMM) * (N_E / BNN), 256, 0, stream>>>(
        Ahi, Alo, Bhi, Blo, keys);
    k_gather<<<N_PTS / 4, 256, 0, stream>>>(u, cb, keys, out, counts, loss_sum);
    k_final<<<1, 256, 0, stream>>>(counts, loss_sum, out);
}

// Round 4
// 164.239 us; speedup vs baseline: 5.6045x; 1.3791x over previous
//
#include <hip/hip_runtime.h>
#include <hip/hip_bf16.h>
#include <stdint.h>

#define N_PTS   8192
#define D       256
#define N_E     8192
#define BETA    0.25f
#define EPS_1   1.0000001f   // 1 + 1e-7 (rounds to 1+ulp in f32, same as jnp)

typedef unsigned long long u64;
typedef __attribute__((ext_vector_type(8))) short bf16x8;   // 8 bf16 = 4 VGPR
typedef __attribute__((ext_vector_type(8))) short short8;
typedef __attribute__((ext_vector_type(4))) float f32x4;

// ---- workspace layout (bytes) ----
// Fragment-linear bf16 arrays: element (p,k) of an 8192x256 matrix lives at
//   blk = (p>>4)*8 + (k>>5);  l = ((k>>3)&3)*16 + (p&15);  j = k&7
//   idx = blk*512 + l*8 + j
// Each 16x32 MFMA fragment is a contiguous 1KB block in lane-major order:
// global_load_lds(uniform base + lane*16) and ds_read_b128(lane*16) are both
// perfectly linear -> zero bank conflicts (verified round 3: conflicts = 0).
#define WS_KEYS   0
#define WS_COUNTS (N_PTS * 8)                    // 64 KB
#define WS_LOSS   (WS_COUNTS + N_E * 4)          // +32 KB
#define WS_AHI    (1 << 20)                      // 1 MB-aligned
#define WS_ALO    (WS_AHI + N_PTS * D * 2)
#define WS_BHI    (WS_ALO + N_PTS * D * 2)
#define WS_BLO    (WS_BHI + N_E * D * 2)         // total ~17 MB

__device__ __forceinline__ short f2bf(float x) {
    __hip_bfloat16 h = __float2bfloat16(x);      // RTN-even
    return *reinterpret_cast<short*>(&h);
}
__device__ __forceinline__ float bf2f(short s) {
    __hip_bfloat16 h = *reinterpret_cast<__hip_bfloat16*>(&s);
    return __bfloat162float(h);
}

#define GLOAD16(gp, lp) __builtin_amdgcn_global_load_lds(                      \
    (const __attribute__((address_space(1))) void*)(gp),                       \
    (__attribute__((address_space(3))) void*)(lp), 16, 0, 0)

// ------- init + split f32 -> bf16 hi/lo, fragment-linear layout -------------
__global__ __launch_bounds__(256) void k_prep(
    const float* __restrict__ u, const float* __restrict__ cb,
    short* __restrict__ Ahi, short* __restrict__ Alo,
    short* __restrict__ Bhi, short* __restrict__ Blo,
    u64* __restrict__ keys, float* __restrict__ counts,
    double* __restrict__ loss_sum)
{
    const int tid = blockIdx.x * 256 + threadIdx.x;   // 0 .. 262143
    if (tid < N_E)   counts[tid] = 0.f;
    if (tid < N_PTS) keys[tid] = ~0ULL;
    if (tid == 0)    *loss_sum = 0.0;

    const int blk = tid >> 6;            // = (p>>4)*8 + (k>>5)
    const int l   = tid & 63;
    const int s   = blk >> 3, c = blk & 7;
    const int p   = s * 16 + (l & 15);
    const int k   = c * 32 + (l >> 4) * 8;
    const size_t gin  = (size_t)p * D + k;
    const size_t gout = (size_t)tid * 8;

    float v[8];
    short8 h8, l8;

    *(float4*)&v[0] = *(const float4*)&u[gin];
    *(float4*)&v[4] = *(const float4*)&u[gin + 4];
    if (k == 0) v[0] = -v[0];            // Minkowski sign fold on time comp
    #pragma unroll
    for (int j = 0; j < 8; ++j) {
        h8[j] = f2bf(v[j]);
        l8[j] = f2bf(v[j] - bf2f(h8[j]));
    }
    *(short8*)&Ahi[gout] = h8;
    *(short8*)&Alo[gout] = l8;

    *(float4*)&v[0] = *(const float4*)&cb[gin];
    *(float4*)&v[4] = *(const float4*)&cb[gin + 4];
    #pragma unroll
    for (int j = 0; j < 8; ++j) {
        h8[j] = f2bf(v[j]);
        l8[j] = f2bf(v[j] - bf2f(h8[j]));
    }
    *(short8*)&Bhi[gout] = h8;
    *(short8*)&Blo[gout] = l8;
}

// ---------------- MFMA argmin: C = A~ . B^T, per-row argmin, no C write ------
// split-bf16: a.b = ahi.bhi + ahi.blo + alo.bhi  (err ~2^-18 rel, safe margin)
#define BMM 128
#define BNN 128
#define BKK 32
#define NKS (D / BKK)        // 8

__global__ __launch_bounds__(256, 4) void k_argmin_mfma(
    const short* __restrict__ Ahi, const short* __restrict__ Alo,
    const short* __restrict__ Bhi, const short* __restrict__ Blo,
    u64* __restrict__ keys)
{
    __shared__ short sm[4][8 * 512];     // Ahi,Alo,Bhi,Blo: 8 KB each = 32 KB

    const int t   = threadIdx.x;
    const int w   = t >> 6;              // wave 0..3
    const int l   = t & 63;
    // NATURAL block order (round-2 locality): consecutive blocks share the
    // A-panel and round-robin across XCDs -> each XCD reuses a fixed residue
    // class of 8 B-panels (2 MB, L2-fit). Explicit XCD swizzle REGRESSED
    // (round 3: FETCH 250 MB, L2 thrash) since all data is L3-fit.
    const int rb  = blockIdx.x >> 6;     // 64 row-blocks (points)
    const int cbk = blockIdx.x & 63;     // 64 col-blocks (codes)
    const int r0  = rb * BMM, c0 = cbk * BNN;
    const int wr  = w >> 1, wc = w & 1;  // 2x2 wave grid, 64x64 each

    // staging: wave w owns one array; 8 fragment-blocks of 1KB per K-step
    const short* gsrc = (w == 0) ? Ahi : (w == 1) ? Alo : (w == 2) ? Bhi : Blo;
    short* ldst = sm[w];
    const int s0 = ((w < 2) ? rb : cbk) * 8;   // first 16-row slice index

    f32x4 acc[4][4];
    #pragma unroll
    for (int i = 0; i < 4; ++i)
        #pragma unroll
        for (int j = 0; j < 4; ++j) acc[i][j] = (f32x4){0.f, 0.f, 0.f, 0.f};

    for (int kk = 0; kk < NKS; ++kk) {
        __syncthreads();                 // prev compute done before overwrite
        #pragma unroll
        for (int i = 0; i < 8; ++i)
            GLOAD16(gsrc + (size_t)((s0 + i) * 8 + kk) * 512 + l * 8,
                    ldst + i * 512);
        __syncthreads();                 // drains vmcnt: tiles ready

        bf16x8 ah[4], al[4], bh[4], bl[4];
        #pragma unroll
        for (int f = 0; f < 4; ++f) {
            ah[f] = *(const bf16x8*)&sm[0][(wr * 4 + f) * 512 + l * 8];
            al[f] = *(const bf16x8*)&sm[1][(wr * 4 + f) * 512 + l * 8];
            bh[f] = *(const bf16x8*)&sm[2][(wc * 4 + f) * 512 + l * 8];
            bl[f] = *(const bf16x8*)&sm[3][(wc * 4 + f) * 512 + l * 8];
        }
        #pragma unroll
        for (int mf = 0; mf < 4; ++mf)
            #pragma unroll
            for (int nf = 0; nf < 4; ++nf) {
                acc[mf][nf] = __builtin_amdgcn_mfma_f32_16x16x32_bf16(
                    ah[mf], bh[nf], acc[mf][nf], 0, 0, 0);
                acc[mf][nf] = __builtin_amdgcn_mfma_f32_16x16x32_bf16(
                    ah[mf], bl[nf], acc[mf][nf], 0, 0, 0);
                acc[mf][nf] = __builtin_amdgcn_mfma_f32_16x16x32_bf16(
                    al[mf], bh[nf], acc[mf][nf], 0, 0, 0);
            }
    }

    // epilogue: per-row argmin over this block's 128 codes, then atomicMin
    // C/D layout (m89-verified): col = lane&15, row = (lane>>4)*4 + reg
    const int g  = l >> 4;
    const int cc = l & 15;
    #pragma unroll
    for (int mf = 0; mf < 4; ++mf) {
        #pragma unroll
        for (int r = 0; r < 4; ++r) {
            u64 km = ~0ULL;
            #pragma unroll
            for (int nf = 0; nf < 4; ++nf) {
                float m = fmaxf(-acc[mf][nf][r], EPS_1);   // m >= 1 > 0
                unsigned code = (unsigned)(c0 + wc * 64 + nf * 16 + cc);
                u64 key = ((u64)__float_as_uint(m) << 32) | code;
                km = key < km ? key : km;
            }
            #pragma unroll
            for (int s = 8; s >= 1; s >>= 1) {             // 16-lane col groups
                u64 o = __shfl_xor(km, s);
                km = o < km ? o : km;
            }
            if (cc == 0)
                atomicMin(&keys[r0 + wr * 64 + mf * 16 + g * 4 + r], km);
        }
    }
}

// ---------------- gather z_q, per-pair f32 distance, histogram ----------------
__global__ __launch_bounds__(256) void k_gather(
    const float* __restrict__ u, const float* __restrict__ cb,
    const u64* __restrict__ keys, float* __restrict__ out,
    float* __restrict__ counts, double* __restrict__ loss_sum)
{
    __shared__ float sred[4];
    const int t    = threadIdx.x;
    const int w    = t >> 6;
    const int row  = blockIdx.x * 4 + w;
    const int lane = t & 63;
    const u64 key  = keys[row];
    const int idx  = (int)(unsigned)(key & 0xffffffffULL);

    float* zq = out + 1;
    float4 uv = *(const float4*)&u[(size_t)row * D + lane * 4];
    float4 cv = *(const float4*)&cb[(size_t)idx * D + lane * 4];
    if (lane == 0) uv.x = -uv.x;                  // Lorentzian sign
    float partial = uv.x * cv.x + uv.y * cv.y + uv.z * cv.z + uv.w * cv.w;
    *(float4*)&zq[(size_t)row * D + lane * 4] = cv;

    #pragma unroll
    for (int s = 32; s >= 1; s >>= 1)
        partial += __shfl_xor(partial, s);

    if (lane == 0) {
        float m = fmaxf(-partial, EPS_1);
        sred[w] = acoshf(m);
        atomicAdd(&counts[idx], 1.f);             // scattered: low contention
    }
    __syncthreads();
    if (t == 0)                                   // 1 f64 atomic per block
        atomicAdd(loss_sum, (double)(sred[0] + sred[1] + sred[2] + sred[3]));
}

// ---------------- scalars: loss, perplexity, entropy, e_mean -----------------
__global__ __launch_bounds__(256) void k_final(
    const float* __restrict__ counts, const double* __restrict__ loss_sum,
    float* __restrict__ out)
{
    __shared__ float red[256];
    const int t = threadIdx.x;
    const int OFF_P = 1 + N_PTS * D;
    float ent = 0.f;
    for (int i = t; i < N_E; i += 256) {
        float e = counts[i] * (1.0f / N_PTS);
        out[OFF_P + 2 + i] = e;
        ent -= e * logf(e + 1e-10f);
    }
    red[t] = ent;
    __syncthreads();
    for (int s = 128; s > 0; s >>= 1) {
        if (t < s) red[t] += red[t + s];
        __syncthreads();
    }
    if (t == 0) {
        float entropy = red[0];
        out[0]         = (1.0f + BETA) * (float)(*loss_sum / (double)N_PTS);
        out[OFF_P]     = expf(entropy);
        out[OFF_P + 1] = entropy;
    }
}

// ---------------- launch ----------------
extern "C" void kernel_launch(void* const* d_in, const int* in_sizes, int n_in,
                              void* d_out, int out_size, void* d_ws, size_t ws_size,
                              hipStream_t stream)
{
    const float* u  = (const float*)d_in[0];
    const float* cb = (const float*)d_in[1];
    float* out = (float*)d_out;
    char* ws = (char*)d_ws;

    u64*    keys     = (u64*)(ws + WS_KEYS);
    float*  counts   = (float*)(ws + WS_COUNTS);
    double* loss_sum = (double*)(ws + WS_LOSS);
    short*  Ahi = (short*)(ws + WS_AHI);
    short*  Alo = (short*)(ws + WS_ALO);
    short*  Bhi = (short*)(ws + WS_BHI);
    short*  Blo = (short*)(ws + WS_BLO);

    k_prep<<<N_PTS * D / 8 / 256, 256, 0, stream>>>(u, cb, Ahi, Alo, Bhi, Blo,
                                                    keys, counts, loss_sum);
    k_argmin_mfma<<<(N_PTS / BMM) * (N_E / BNN), 256, 0, stream>>>(
        Ahi, Alo, Bhi, Blo, keys);
    k_gather<<<N_PTS / 4, 256, 0, stream>>>(u, cb, keys, out, counts, loss_sum);
    k_final<<<1, 256, 0, stream>>>(counts, loss_sum, out);
}